// Round 7
// baseline (1144.401 us; speedup 1.0000x reference)
//
#include <hip/hip_runtime.h>
#include <hip/hip_bf16.h>

#define HW   65536
#define CHW  (128*65536)
// token-major qkv: [oz][b][head][win][tok][d] bf16; strides in elements:
#define QKV_OZ  33554432u   // 4*8*1024*64*16
#define QKV_H   1048576u    // 1024*64*16
#define QKV_WIN 1024u       // 64*16

typedef __attribute__((ext_vector_type(8))) short bf16x8;
typedef __attribute__((ext_vector_type(4))) short bf16x4;
typedef __attribute__((ext_vector_type(4))) float f32x4;

__device__ __forceinline__ float geluf(float v){
    // tanh-form GELU, overflow-safe. max abs dev from exact erf-GELU ~1e-3.
    float u = 0.7978845608028654f * v * (1.f + 0.044715f*v*v);
    float e = __expf(2.f*u);
    float th = 1.f - 2.f/(e+1.f);
    return 0.5f*v*(1.f+th);
}

__device__ __forceinline__ float sigmoidf_(float z){
    return 1.f / (1.f + __expf(-z));
}

__device__ __forceinline__ float bf2f(short s){
    return __uint_as_float(((unsigned)(unsigned short)s) << 16);
}

// ---------------- K0: f32 -> bf16 weight conversion ----------------
__global__ __launch_bounds__(256) void k_cvt(
    const float* __restrict__ src, __hip_bfloat16* __restrict__ dst, int n)
{
    int i = blockIdx.x*256 + threadIdx.x;
    if (i < n) dst[i] = __float2bfloat16(src[i]);
}

// ---------------- K1: LN1 + QKV GEMM (MFMA) + gate(q) -> qkv bf16 (token-major) ----------------
// launch_bounds (256,3): cap regs ~170 -> 3 waves/SIMD (was 2). Latency-bound kernel.
__global__ __launch_bounds__(256,3) void k_ln_qkv_mfma(
    const float* __restrict__ x, const float* __restrict__ l0,
    const float* __restrict__ n1w, const float* __restrict__ n1b,
    const __hip_bfloat16* __restrict__ qkvw, const float* __restrict__ gate_w,
    const float* __restrict__ gate_b, __hip_bfloat16* __restrict__ qkvb)
{
    __shared__ short sxb[128*130];      // [px][128 bf16 + 2 pad] = 65 dwords/row, odd -> conflict-free
    __shared__ float sp1[256], sp2[256];
    const int t = threadIdx.x;
    const int lane = t & 63, w = t >> 6;
    const int l15 = lane & 15, q4 = (lane >> 4)*4, ko = (lane >> 4)*8;
    const int mhalf = w & 1, phalf = w >> 1;
    const int pbase = blockIdx.x * 128;
    const int b = pbase >> 16;
    const int hw0 = pbase & 65535;
    const int x0 = hw0 & 255;           // 0 or 128 (tile stays in one image row)
    const int y  = hw0 >> 8;
    const int wy = y >> 3, ty = y & 7;
    const int pxs = t & 127, chalf = t >> 7;   // 2 threads per pixel, 64 channels each
    const float* xb = x + (size_t)b*CHW + (size_t)chalf*64*HW + hw0 + pxs;
    unsigned* srow = (unsigned*)sxb + pxs*65 + chalf*32;

    float s1 = 0.f, s2 = 0.f;
    #pragma unroll 8
    for (int j = 0; j < 32; ++j) {
        float v0 = xb[(size_t)(2*j)*HW];
        float v1 = xb[(size_t)(2*j+1)*HW];
        s1 += v0 + v1; s2 += v0*v0 + v1*v1;
        __hip_bfloat162 pk = __float22bfloat162_rn(make_float2(v0, v1));
        srow[j] = *(unsigned*)&pk;
    }
    sp1[pxs*2 + chalf] = s1;
    sp2[pxs*2 + chalf] = s2;
    __syncthreads();
    const float s1t = sp1[pxs*2] + sp1[pxs*2 + 1];
    const float s2t = sp2[pxs*2] + sp2[pxs*2 + 1];
    const float mean = s1t * 0.0078125f;
    const float rstd = rsqrtf(s2t*0.0078125f - mean*mean + 1e-6f);
    #pragma unroll 8
    for (int j = 0; j < 32; ++j) {
        unsigned u = srow[j];
        float v0 = __uint_as_float(u << 16);
        float v1 = __uint_as_float(u & 0xffff0000u);
        const int c = chalf*64 + 2*j;
        v0 = (v0 - mean)*rstd*n1w[c]   + n1b[c];
        v1 = (v1 - mean)*rstd*n1w[c+1] + n1b[c+1];
        __hip_bfloat162 pk = __float22bfloat162_rn(make_float2(v0, v1));
        srow[j] = *(unsigned*)&pk;
    }
    __syncthreads();

    float lv[4];
    #pragma unroll
    for (int nt = 0; nt < 4; ++nt)
        lv[nt] = l0[(size_t)b*HW + hw0 + phalf*64 + nt*16 + l15];

    unsigned toff[4];
    #pragma unroll
    for (int nt = 0; nt < 4; ++nt) {
        const int xg = x0 + phalf*64 + nt*16 + l15;
        toff[nt] = (unsigned)((wy*32 + (xg >> 3))*1024 + (ty*8 + (xg & 7))*16);
    }

    const short* wq = (const short*)qkvw;
    for (int oz = 0; oz < 3; ++oz) {
        f32x4 acc[4][4];
        #pragma unroll
        for (int mt = 0; mt < 4; ++mt)
            #pragma unroll
            for (int nt = 0; nt < 4; ++nt)
                acc[mt][nt] = (f32x4){0.f,0.f,0.f,0.f};
        #pragma unroll
        for (int kc = 0; kc < 4; ++kc) {
            bf16x8 bfrag[4];
            #pragma unroll
            for (int nt = 0; nt < 4; ++nt) {
                const int px = phalf*64 + nt*16 + l15;
                bfrag[nt] = *(const bf16x8*)(sxb + px*130 + kc*32 + ko);
            }
            #pragma unroll
            for (int mt = 0; mt < 4; ++mt) {
                const int m = oz*128 + mhalf*64 + mt*16 + l15;
                bf16x8 af = *(const bf16x8*)(wq + m*128 + kc*32 + ko);
                #pragma unroll
                for (int nt = 0; nt < 4; ++nt)
                    acc[mt][nt] = __builtin_amdgcn_mfma_f32_16x16x32_bf16(af, bfrag[nt], acc[mt][nt], 0, 0, 0);
            }
        }
        __hip_bfloat16* ob = qkvb + (size_t)oz*QKV_OZ + (size_t)b*8*QKV_H;
        #pragma unroll
        for (int mt = 0; mt < 4; ++mt) {
            const int h = mhalf*4 + mt;
            #pragma unroll
            for (int nt = 0; nt < 4; ++nt) {
                float v0 = acc[mt][nt][0], v1 = acc[mt][nt][1];
                float v2 = acc[mt][nt][2], v3 = acc[mt][nt][3];
                if (oz == 0) {
                    const int o = h*16 + q4;
                    v0 *= sigmoidf_(lv[nt]*gate_w[o]   + gate_b[o]);
                    v1 *= sigmoidf_(lv[nt]*gate_w[o+1] + gate_b[o+1]);
                    v2 *= sigmoidf_(lv[nt]*gate_w[o+2] + gate_b[o+2]);
                    v3 *= sigmoidf_(lv[nt]*gate_w[o+3] + gate_b[o+3]);
                }
                __hip_bfloat162 p0 = __float22bfloat162_rn(make_float2(v0, v1));
                __hip_bfloat162 p1 = __float22bfloat162_rn(make_float2(v2, v3));
                uint2 st;
                st.x = *(unsigned*)&p0;
                st.y = *(unsigned*)&p1;
                *(uint2*)(ob + (size_t)h*QKV_H + toff[nt] + q4) = st;
            }
        }
    }
}

// ---------------- K2: windowed attention, MFMA (token-major bf16 qkv in, f32 out) --------
__global__ __launch_bounds__(256) void k_attn(
    const __hip_bfloat16* __restrict__ qkv, float* __restrict__ attn_out)
{
    __shared__ short vt[4][16*72];            // per-wave V^T: [d][tok], stride 72
    __shared__ short pt[4][64*68];            // per-wave P^T: [i][j], stride 68
    const int t = threadIdx.x;
    const int l = t & 63, w = t >> 6;
    const int c = l & 15, g = l >> 4;
    const int id = blockIdx.x*4 + w;          // b(2) | head(3) | win(10)
    const int b = id >> 13;
    const int head = (id >> 10) & 7;
    const int wi = id & 1023;
    const __hip_bfloat16* qp = qkv + ((size_t)(b*8 + head))*QKV_H + (size_t)wi*QKV_WIN;
    const __hip_bfloat16* kp = qp + QKV_OZ;
    const __hip_bfloat16* vp = qp + 2u*QKV_OZ;

    // stage V^T: lane l owns token l (16 d-values -> 16 scalar LDS writes, 2-way=free)
    bf16x8 v0 = *(const bf16x8*)(vp + l*16);
    bf16x8 v1 = *(const bf16x8*)(vp + l*16 + 8);
    short* vtw = &vt[w][0];
    #pragma unroll
    for (int d = 0; d < 8; ++d) vtw[d*72 + l] = v0[d];
    #pragma unroll
    for (int d = 0; d < 8; ++d) vtw[(8+d)*72 + l] = v1[d];

    // Q/K fragments: lane g<2 holds d-slice g*8..g*8+7 of token (tile*16 + c); g>=2 zero.
    bf16x8 kf[4], qf[4];
    #pragma unroll
    for (int mj = 0; mj < 4; ++mj) {
        if (g < 2) {
            kf[mj] = *(const bf16x8*)(kp + (mj*16 + c)*16 + g*8);
            qf[mj] = *(const bf16x8*)(qp + (mj*16 + c)*16 + g*8);
        } else {
            kf[mj] = (bf16x8){0,0,0,0,0,0,0,0};
            qf[mj] = (bf16x8){0,0,0,0,0,0,0,0};
        }
    }
    // S^T tiles: st[mj][ni]: j = mj*16 + g*4 + r, i = ni*16 + c
    f32x4 st[4][4];
    #pragma unroll
    for (int mj = 0; mj < 4; ++mj)
        #pragma unroll
        for (int ni = 0; ni < 4; ++ni)
            st[mj][ni] = (f32x4){0.f,0.f,0.f,0.f};
    #pragma unroll
    for (int mj = 0; mj < 4; ++mj)
        #pragma unroll
        for (int ni = 0; ni < 4; ++ni)
            st[mj][ni] = __builtin_amdgcn_mfma_f32_16x16x32_bf16(kf[mj], qf[ni], st[mj][ni], 0, 0, 0);

    // softmax over keys j (per query i = ni*16+c); scale 0.25 folded in
    float rs[4];
    bf16x4 pa[4][4], pb[4][4];      // hi/lo bf16 of P^T, [mj][ni]
    #pragma unroll
    for (int ni = 0; ni < 4; ++ni) {
        float mx = -1e30f;
        #pragma unroll
        for (int mj = 0; mj < 4; ++mj)
            #pragma unroll
            for (int r = 0; r < 4; ++r)
                mx = fmaxf(mx, st[mj][ni][r]);
        mx = fmaxf(mx, __shfl_xor(mx, 16));
        mx = fmaxf(mx, __shfl_xor(mx, 32));
        mx *= 0.25f;
        float sum = 0.f;
        #pragma unroll
        for (int mj = 0; mj < 4; ++mj) {
            float p[4], lo[4];
            #pragma unroll
            for (int r = 0; r < 4; ++r) {
                p[r] = __expf(st[mj][ni][r]*0.25f - mx);
                sum += p[r];
            }
            __hip_bfloat162 h0 = __float22bfloat162_rn(make_float2(p[0], p[1]));
            __hip_bfloat162 h1 = __float22bfloat162_rn(make_float2(p[2], p[3]));
            union { unsigned u[2]; bf16x4 v; } hi;
            hi.u[0] = *(unsigned*)&h0; hi.u[1] = *(unsigned*)&h1;
            pa[mj][ni] = hi.v;
            #pragma unroll
            for (int r = 0; r < 4; ++r) lo[r] = p[r] - bf2f(hi.v[r]);
            __hip_bfloat162 g0 = __float22bfloat162_rn(make_float2(lo[0], lo[1]));
            __hip_bfloat162 g1 = __float22bfloat162_rn(make_float2(lo[2], lo[3]));
            union { unsigned u[2]; bf16x4 v; } lw;
            lw.u[0] = *(unsigned*)&g0; lw.u[1] = *(unsigned*)&g1;
            pb[mj][ni] = lw.v;
        }
        sum += __shfl_xor(sum, 16);
        sum += __shfl_xor(sum, 32);
        rs[ni] = 1.f / sum;
    }

    // PV: O^T[d][i] = sum_j V^T[d][j] * P^T[j][i], K=32 x 2 chunks, hi then lo pass.
    short* ptw = &pt[w][0];
    f32x4 oc[4];
    #pragma unroll
    for (int ni = 0; ni < 4; ++ni) oc[ni] = (f32x4){0.f,0.f,0.f,0.f};
    bf16x8 vf[2];
    #pragma unroll
    for (int kb = 0; kb < 2; ++kb)
        vf[kb] = *(const bf16x8*)(vtw + c*72 + kb*32 + g*8);

    // hi pass
    #pragma unroll
    for (int mj = 0; mj < 4; ++mj)
        #pragma unroll
        for (int ni = 0; ni < 4; ++ni)
            *(bf16x4*)(ptw + (ni*16 + c)*68 + mj*16 + g*4) = pa[mj][ni];
    __syncthreads();
    #pragma unroll
    for (int kb = 0; kb < 2; ++kb)
        #pragma unroll
        for (int ni = 0; ni < 4; ++ni) {
            bf16x8 pf = *(const bf16x8*)(ptw + (ni*16 + c)*68 + kb*32 + g*8);
            oc[ni] = __builtin_amdgcn_mfma_f32_16x16x32_bf16(vf[kb], pf, oc[ni], 0, 0, 0);
        }
    __syncthreads();
    // lo pass (reuse buffer)
    #pragma unroll
    for (int mj = 0; mj < 4; ++mj)
        #pragma unroll
        for (int ni = 0; ni < 4; ++ni)
            *(bf16x4*)(ptw + (ni*16 + c)*68 + mj*16 + g*4) = pb[mj][ni];
    __syncthreads();
    #pragma unroll
    for (int kb = 0; kb < 2; ++kb)
        #pragma unroll
        for (int ni = 0; ni < 4; ++ni) {
            bf16x8 pf = *(const bf16x8*)(ptw + (ni*16 + c)*68 + kb*32 + g*8);
            oc[ni] = __builtin_amdgcn_mfma_f32_16x16x32_bf16(vf[kb], pf, oc[ni], 0, 0, 0);
        }

    const int wy = wi >> 5, wx = wi & 31;
    float* ob = attn_out + (size_t)b*CHW + (size_t)(head*16)*HW + (size_t)(wy*8)*256 + wx*8;
    #pragma unroll
    for (int ni = 0; ni < 4; ++ni) {
        const int tok = ni*16 + c;
        float* o2 = ob + (tok >> 3)*256 + (tok & 7);
        #pragma unroll
        for (int r = 0; r < 4; ++r) {
            const int d = g*4 + r;
            o2[(size_t)d*HW] = oc[ni][r] * rs[ni];
        }
    }
}

// ---------------- K3: proj (MFMA) + bias + shortcut, in-place on d_out ----------------
__global__ __launch_bounds__(256,3) void k_proj_mfma(
    const float* __restrict__ x, const __hip_bfloat16* __restrict__ projw,
    const float* __restrict__ proj_b, float* __restrict__ out)
{
    __shared__ short sxb[128*130];
    const int t = threadIdx.x;
    const int lane = t & 63, w = t >> 6;
    const int l15 = lane & 15, q4 = (lane >> 4)*4, ko = (lane >> 4)*8;
    const int mhalf = w & 1, phalf = w >> 1;
    const int pbase = blockIdx.x * 128;
    const int b = pbase >> 16;
    const int hw0 = pbase & 65535;
    const int pxs = t & 127, chalf = t >> 7;
    const float* ab = out + (size_t)b*CHW + (size_t)chalf*64*HW + hw0 + pxs;
    unsigned* srow = (unsigned*)sxb + pxs*65 + chalf*32;
    #pragma unroll 8
    for (int j = 0; j < 32; ++j) {
        float v0 = ab[(size_t)(2*j)*HW];
        float v1 = ab[(size_t)(2*j+1)*HW];
        __hip_bfloat162 pk = __float22bfloat162_rn(make_float2(v0, v1));
        srow[j] = *(unsigned*)&pk;
    }
    __syncthreads();
    f32x4 acc[4][4];
    #pragma unroll
    for (int mt = 0; mt < 4; ++mt)
        #pragma unroll
        for (int nt = 0; nt < 4; ++nt)
            acc[mt][nt] = (f32x4){0.f,0.f,0.f,0.f};
    const short* wp = (const short*)projw;
    #pragma unroll
    for (int kc = 0; kc < 4; ++kc) {
        bf16x8 bfrag[4];
        #pragma unroll
        for (int nt = 0; nt < 4; ++nt) {
            const int px = phalf*64 + nt*16 + l15;
            bfrag[nt] = *(const bf16x8*)(sxb + px*130 + kc*32 + ko);
        }
        #pragma unroll
        for (int mt = 0; mt < 4; ++mt) {
            const int m = mhalf*64 + mt*16 + l15;
            bf16x8 af = *(const bf16x8*)(wp + m*128 + kc*32 + ko);
            #pragma unroll
            for (int nt = 0; nt < 4; ++nt)
                acc[mt][nt] = __builtin_amdgcn_mfma_f32_16x16x32_bf16(af, bfrag[nt], acc[mt][nt], 0, 0, 0);
        }
    }
    const float* xb = x + (size_t)b*CHW + hw0;
    float* ob = out + (size_t)b*CHW + hw0;
    #pragma unroll
    for (int mt = 0; mt < 4; ++mt)
        #pragma unroll
        for (int nt = 0; nt < 4; ++nt) {
            const int px = phalf*64 + nt*16 + l15;
            #pragma unroll
            for (int r = 0; r < 4; ++r) {
                const int o = mhalf*64 + mt*16 + q4 + r;
                ob[(size_t)o*HW + px] = acc[mt][nt][r] + proj_b[o] + xb[(size_t)o*HW + px];
            }
        }
}

// ---------------- K4: LN2 + FFN1 (MFMA) + bias + GELU -> h1 bf16 (PER BATCH) ----------------
__global__ __launch_bounds__(256,3) void k_ffn1_mfma(
    const float* __restrict__ outb, const float* __restrict__ n2w, const float* __restrict__ n2b,
    const __hip_bfloat16* __restrict__ w1, const float* __restrict__ b1,
    __hip_bfloat16* __restrict__ h1s)
{
    __shared__ short sxb[128*130];
    __shared__ float sp1[256], sp2[256];
    const int t = threadIdx.x;
    const int lane = t & 63, w = t >> 6;
    const int l15 = lane & 15, q4 = (lane >> 4)*4, ko = (lane >> 4)*8;
    const int mhalf = w & 1, phalf = w >> 1;
    const int hw0 = blockIdx.x * 128;
    const int pxs = t & 127, chalf = t >> 7;
    const float* xb = outb + (size_t)chalf*64*HW + hw0 + pxs;
    unsigned* srow = (unsigned*)sxb + pxs*65 + chalf*32;
    float s1 = 0.f, s2 = 0.f;
    #pragma unroll 8
    for (int j = 0; j < 32; ++j) {
        float v0 = xb[(size_t)(2*j)*HW];
        float v1 = xb[(size_t)(2*j+1)*HW];
        s1 += v0 + v1; s2 += v0*v0 + v1*v1;
        __hip_bfloat162 pk = __float22bfloat162_rn(make_float2(v0, v1));
        srow[j] = *(unsigned*)&pk;
    }
    sp1[pxs*2 + chalf] = s1;
    sp2[pxs*2 + chalf] = s2;
    __syncthreads();
    const float s1t = sp1[pxs*2] + sp1[pxs*2 + 1];
    const float s2t = sp2[pxs*2] + sp2[pxs*2 + 1];
    const float mean = s1t * 0.0078125f;
    const float rstd = rsqrtf(s2t*0.0078125f - mean*mean + 1e-6f);
    #pragma unroll 8
    for (int j = 0; j < 32; ++j) {
        unsigned u = srow[j];
        float v0 = __uint_as_float(u << 16);
        float v1 = __uint_as_float(u & 0xffff0000u);
        const int c = chalf*64 + 2*j;
        v0 = (v0 - mean)*rstd*n2w[c]   + n2b[c];
        v1 = (v1 - mean)*rstd*n2w[c+1] + n2b[c+1];
        __hip_bfloat162 pk = __float22bfloat162_rn(make_float2(v0, v1));
        srow[j] = *(unsigned*)&pk;
    }
    __syncthreads();
    const short* w1s = (const short*)w1;
    __hip_bfloat16* hb = h1s + hw0;
    for (int mc = 0; mc < 4; ++mc) {
        f32x4 acc[4][4];
        #pragma unroll
        for (int mt = 0; mt < 4; ++mt)
            #pragma unroll
            for (int nt = 0; nt < 4; ++nt)
                acc[mt][nt] = (f32x4){0.f,0.f,0.f,0.f};
        #pragma unroll
        for (int kc = 0; kc < 4; ++kc) {
            bf16x8 bfrag[4];
            #pragma unroll
            for (int nt = 0; nt < 4; ++nt) {
                const int px = phalf*64 + nt*16 + l15;
                bfrag[nt] = *(const bf16x8*)(sxb + px*130 + kc*32 + ko);
            }
            #pragma unroll
            for (int mt = 0; mt < 4; ++mt) {
                const int m = mc*128 + mhalf*64 + mt*16 + l15;
                bf16x8 af = *(const bf16x8*)(w1s + m*128 + kc*32 + ko);
                #pragma unroll
                for (int nt = 0; nt < 4; ++nt)
                    acc[mt][nt] = __builtin_amdgcn_mfma_f32_16x16x32_bf16(af, bfrag[nt], acc[mt][nt], 0, 0, 0);
            }
        }
        #pragma unroll
        for (int mt = 0; mt < 4; ++mt)
            #pragma unroll
            for (int nt = 0; nt < 4; ++nt) {
                const int px = phalf*64 + nt*16 + l15;
                #pragma unroll
                for (int r = 0; r < 4; ++r) {
                    const int o = mc*128 + mhalf*64 + mt*16 + q4 + r;
                    const float v = geluf(acc[mt][nt][r] + b1[o]);
                    hb[(size_t)o*HW + px] = __float2bfloat16(v);
                }
            }
    }
}

// ---------------- K5a: depthwise 3x3 + GELU on channel PAIRS -> h2 (pair-interleaved bf16) ----
__global__ __launch_bounds__(256) void k_dwconv(
    const __hip_bfloat16* __restrict__ h1b,   // batch base: [512][HW] bf16
    unsigned* __restrict__ h2u,               // [256][HW] pair-packed
    const float* __restrict__ dwf, const float* __restrict__ dwb)
{
    __shared__ short sh[2*18*260];            // 2 ch x 18 rows x (2 + 256 + 1 + pad) cols
    const int t = threadIdx.x;
    const int rb = blockIdx.x & 15;
    const int cp = blockIdx.x >> 4;           // channel pair 0..255
    const int row0 = rb * 16;
    #pragma unroll
    for (int ch = 0; ch < 2; ++ch) {
        const __hip_bfloat16* src = h1b + (size_t)(cp*2 + ch)*HW;
        #pragma unroll
        for (int i = 0; i < 9; ++i) {
            const int idx = t + i*256;
            const int r = idx >> 7;           // 0..17
            const int u = idx & 127;          // uint col (2 pixels)
            const int y = row0 - 1 + r;
            unsigned v = 0u;
            if ((unsigned)y < 256u) v = *(const unsigned*)(src + (size_t)y*256 + u*2);
            *(unsigned*)(&sh[ch*4680 + r*260 + 2 + u*2]) = v;
        }
    }
    if (t < 72) {
        const int ch = t / 36, q = t - ch*36;
        const int r = q >> 1;
        sh[ch*4680 + r*260 + ((q & 1) ? 258 : 1)] = 0;
    }
    __syncthreads();
    float wt[2][9], bs[2];
    #pragma unroll
    for (int ch = 0; ch < 2; ++ch) {
        const float* dwc = dwf + (size_t)(cp*2 + ch)*9;
        #pragma unroll
        for (int k = 0; k < 9; ++k) wt[ch][k] = dwc[k];
        bs[ch] = dwb[cp*2 + ch];
    }
    const int xp = (t & 127) * 2;   // this thread's output column pair
    const int rh = t >> 7;          // row half (8 rows each)
    #pragma unroll
    for (int r = 0; r < 8; ++r) {
        const int orow = rh*8 + r;            // 0..15 within block
        const int y = row0 + orow;
        float res[2][2];
        #pragma unroll
        for (int ch = 0; ch < 2; ++ch) {
            const short* base = sh + ch*4680 + orow*260 + xp + 1;
            float a[3][4];
            #pragma unroll
            for (int dy = 0; dy < 3; ++dy)
                #pragma unroll
                for (int k = 0; k < 4; ++k)
                    a[dy][k] = __uint_as_float((unsigned)(unsigned short)base[dy*260 + k] << 16);
            #pragma unroll
            for (int xj = 0; xj < 2; ++xj) {
                float s = bs[ch];
                #pragma unroll
                for (int dy = 0; dy < 3; ++dy)
                    #pragma unroll
                    for (int dx = 0; dx < 3; ++dx)
                        s = fmaf(a[dy][xj+dx], wt[ch][dy*3+dx], s);
                res[ch][xj] = geluf(s);
            }
        }
        __hip_bfloat162 pk0 = __float22bfloat162_rn(make_float2(res[0][0], res[1][0]));
        __hip_bfloat162 pk1 = __float22bfloat162_rn(make_float2(res[0][1], res[1][1]));
        uint2 st;
        st.x = *(unsigned*)&pk0;
        st.y = *(unsigned*)&pk1;
        *(uint2*)(h2u + (size_t)cp*HW + (size_t)y*256 + xp) = st;
    }
}

// ---------------- K5b: FFN2 GEMM (128 out x 512 in) + bias + residual, per batch ----------------
__global__ __launch_bounds__(256,3) void k_ffn2g(
    const unsigned* __restrict__ h2u, const __hip_bfloat16* __restrict__ w2b,
    const float* __restrict__ b2, float* __restrict__ outb)
{
    __shared__ short sxb[128*130];            // [px][128 ch + 2 pad]
    const int t = threadIdx.x;
    const int lane = t & 63, w = t >> 6;
    const int l15 = lane & 15, q4 = (lane >> 4)*4, ko = (lane >> 4)*8;
    const int mhalf = w & 1, phalf = w >> 1;
    const int pbase = blockIdx.x * 128;
    const int pxs = t & 127;                  // staging: this thread's pixel row
    const int chalf = t >> 7;                 // staging: channel-pair half
    f32x4 acc[4][4];
    #pragma unroll
    for (int mt = 0; mt < 4; ++mt)
        #pragma unroll
        for (int nt = 0; nt < 4; ++nt)
            acc[mt][nt] = (f32x4){0.f,0.f,0.f,0.f};
    const short* w2s = (const short*)w2b;
    for (int k4 = 0; k4 < 4; ++k4) {
        if (k4) __syncthreads();
        const unsigned* hsrc = h2u + (size_t)(k4*64 + chalf*32)*HW + pbase + pxs;
        unsigned* sdst = (unsigned*)sxb + pxs*65 + chalf*32;
        #pragma unroll
        for (int c = 0; c < 32; ++c)
            sdst[c] = hsrc[(size_t)c*HW];
        __syncthreads();
        #pragma unroll
        for (int kc = 0; kc < 4; ++kc) {
            bf16x8 bfrag[4];
            #pragma unroll
            for (int nt = 0; nt < 4; ++nt) {
                const int px = phalf*64 + nt*16 + l15;
                bfrag[nt] = *(const bf16x8*)(sxb + px*130 + kc*32 + ko);
            }
            #pragma unroll
            for (int mt = 0; mt < 4; ++mt) {
                const int m = mhalf*64 + mt*16 + l15;
                bf16x8 af = *(const bf16x8*)(w2s + (size_t)m*512 + k4*128 + kc*32 + ko);
                #pragma unroll
                for (int nt = 0; nt < 4; ++nt)
                    acc[mt][nt] = __builtin_amdgcn_mfma_f32_16x16x32_bf16(af, bfrag[nt], acc[mt][nt], 0, 0, 0);
            }
        }
    }
    #pragma unroll
    for (int mt = 0; mt < 4; ++mt)
        #pragma unroll
        for (int nt = 0; nt < 4; ++nt) {
            const int px = pbase + phalf*64 + nt*16 + l15;
            #pragma unroll
            for (int r = 0; r < 4; ++r) {
                const int o = mhalf*64 + mt*16 + q4 + r;
                outb[(size_t)o*HW + px] = acc[mt][nt][r] + b2[o] + outb[(size_t)o*HW + px];
            }
        }
}

extern "C" void kernel_launch(void* const* d_in, const int* in_sizes, int n_in,
                              void* d_out, int out_size, void* d_ws, size_t ws_size,
                              hipStream_t stream) {
    const float* x      = (const float*)d_in[0];
    const float* l0     = (const float*)d_in[1];
    const float* n1w    = (const float*)d_in[2];
    const float* n1b    = (const float*)d_in[3];
    const float* n2w    = (const float*)d_in[4];
    const float* n2b    = (const float*)d_in[5];
    const float* qkv_w  = (const float*)d_in[6];
    const float* gate_w = (const float*)d_in[7];
    const float* gate_b = (const float*)d_in[8];
    const float* proj_w = (const float*)d_in[9];
    const float* proj_b = (const float*)d_in[10];
    const float* ffn_w1 = (const float*)d_in[11];
    const float* ffn_b1 = (const float*)d_in[12];
    const float* ffn_dw = (const float*)d_in[13];
    const float* ffn_dwb= (const float*)d_in[14];
    const float* ffn_w2 = (const float*)d_in[15];
    const float* ffn_b2 = (const float*)d_in[16];

    float* out = (float*)d_out;
    // ws layout (max byte touched = 268,828,672 — identical to the proven footprint):
    //   [0,192 MiB)        qkv bf16 token-major (dead after attn; first 64 MiB reused as h2u)
    //   [192,256 MiB)      h1 per-batch slot (64 MiB)
    //   [256 MiB,+384 KiB) bf16 weights
    __hip_bfloat16* qkvb = (__hip_bfloat16*)d_ws;
    unsigned* h2u        = (unsigned*)d_ws;                              // aliases dead qkv
    __hip_bfloat16* h1s  = (__hip_bfloat16*)((char*)d_ws + 201326592);   // 192 MiB
    char* wbase = (char*)d_ws + 268435456;
    __hip_bfloat16* qkvw_b = (__hip_bfloat16*)(wbase);
    __hip_bfloat16* projw_b= (__hip_bfloat16*)(wbase + 98304);
    __hip_bfloat16* w1b    = (__hip_bfloat16*)(wbase + 131072);
    __hip_bfloat16* w2b    = (__hip_bfloat16*)(wbase + 262144);

    k_cvt<<<dim3(192), dim3(256), 0, stream>>>(qkv_w, qkvw_b, 49152);
    k_cvt<<<dim3(64),  dim3(256), 0, stream>>>(proj_w, projw_b, 16384);
    k_cvt<<<dim3(256), dim3(256), 0, stream>>>(ffn_w1, w1b, 65536);
    k_cvt<<<dim3(256), dim3(256), 0, stream>>>(ffn_w2, w2b, 65536);

    k_ln_qkv_mfma<<<dim3(2048), dim3(256), 0, stream>>>(x, l0, n1w, n1b, qkvw_b, gate_w, gate_b, qkvb);
    k_attn       <<<dim3(8192), dim3(256), 0, stream>>>(qkvb, out);
    k_proj_mfma  <<<dim3(2048), dim3(256), 0, stream>>>(x, projw_b, proj_b, out);
    for (int b = 0; b < 4; ++b) {
        k_ffn1_mfma<<<dim3(512),  dim3(256), 0, stream>>>(out + (size_t)b*CHW, n2w, n2b, w1b, ffn_b1, h1s);
        k_dwconv   <<<dim3(4096), dim3(256), 0, stream>>>(h1s, h2u, ffn_dw, ffn_dwb);
        k_ffn2g    <<<dim3(512),  dim3(256), 0, stream>>>(h2u, w2b, ffn_b2, out + (size_t)b*CHW);
    }
}

// Round 8
// 1117.880 us; speedup vs baseline: 1.0237x; 1.0237x over previous
//
#include <hip/hip_runtime.h>
#include <hip/hip_bf16.h>

#define HW   65536
#define CHW  (128*65536)
// token-major qkv: [oz][b][head][win][tok][d] bf16; strides in elements:
#define QKV_OZ  33554432u   // 4*8*1024*64*16
#define QKV_H   1048576u    // 1024*64*16
#define QKV_WIN 1024u       // 64*16

typedef __attribute__((ext_vector_type(8))) short bf16x8;
typedef __attribute__((ext_vector_type(4))) short bf16x4;
typedef __attribute__((ext_vector_type(4))) float f32x4;

__device__ __forceinline__ float geluf(float v){
    // tanh-form GELU, overflow-safe. max abs dev from exact erf-GELU ~1e-3.
    float u = 0.7978845608028654f * v * (1.f + 0.044715f*v*v);
    float e = __expf(2.f*u);
    float th = 1.f - 2.f/(e+1.f);
    return 0.5f*v*(1.f+th);
}

__device__ __forceinline__ float sigmoidf_(float z){
    return 1.f / (1.f + __expf(-z));
}

__device__ __forceinline__ float bf2f(short s){
    return __uint_as_float(((unsigned)(unsigned short)s) << 16);
}

// ---------------- K0: f32 -> bf16 weight conversion ----------------
__global__ __launch_bounds__(256) void k_cvt(
    const float* __restrict__ src, __hip_bfloat16* __restrict__ dst, int n)
{
    int i = blockIdx.x*256 + threadIdx.x;
    if (i < n) dst[i] = __float2bfloat16(src[i]);
}

// ---------------- K1: LN1 + QKV GEMM (MFMA) + gate(q) -> qkv bf16 (token-major) ----------------
// 512 threads / 8 waves; waves split M(4) x px(2): acc[2][4] = 32 regs/wave ->
// 3-4 waves/SIMD from NATURAL register allocation (round-7 lesson: forced caps spill).
__global__ __launch_bounds__(512,2) void k_ln_qkv_mfma(
    const float* __restrict__ x, const float* __restrict__ l0,
    const float* __restrict__ n1w, const float* __restrict__ n1b,
    const __hip_bfloat16* __restrict__ qkvw, const float* __restrict__ gate_w,
    const float* __restrict__ gate_b, __hip_bfloat16* __restrict__ qkvb)
{
    __shared__ short sxb[128*130];      // [px][128 bf16 + 2 pad] = 65 dwords/row, odd -> conflict-free
    __shared__ float sp1[512], sp2[512];
    const int t = threadIdx.x;
    const int lane = t & 63, w = t >> 6;           // 8 waves
    const int l15 = lane & 15, q4 = (lane >> 4)*4, ko = (lane >> 4)*8;
    const int mq = w & 3, phalf = w >> 2;          // M quarter (32 rows), px half (64 px)
    const int pbase = blockIdx.x * 128;
    const int b = pbase >> 16;
    const int hw0 = pbase & 65535;
    const int x0 = hw0 & 255;           // 0 or 128 (tile stays in one image row)
    const int y  = hw0 >> 8;
    const int wy = y >> 3, ty = y & 7;
    const int pxs = t & 127, cq = t >> 7;          // 4 threads per pixel, 32 channels each
    const float* xb = x + (size_t)b*CHW + (size_t)cq*32*HW + hw0 + pxs;
    unsigned* srow = (unsigned*)sxb + pxs*65 + cq*16;

    // pass A: partial LN stats + raw bf16 stash (32 channels per thread)
    float s1 = 0.f, s2 = 0.f;
    #pragma unroll
    for (int j = 0; j < 16; ++j) {
        float v0 = xb[(size_t)(2*j)*HW];
        float v1 = xb[(size_t)(2*j+1)*HW];
        s1 += v0 + v1; s2 += v0*v0 + v1*v1;
        __hip_bfloat162 pk = __float22bfloat162_rn(make_float2(v0, v1));
        srow[j] = *(unsigned*)&pk;
    }
    sp1[pxs*4 + cq] = s1;
    sp2[pxs*4 + cq] = s2;
    __syncthreads();
    const float s1t = sp1[pxs*4] + sp1[pxs*4+1] + sp1[pxs*4+2] + sp1[pxs*4+3];
    const float s2t = sp2[pxs*4] + sp2[pxs*4+1] + sp2[pxs*4+2] + sp2[pxs*4+3];
    const float mean = s1t * 0.0078125f;
    const float rstd = rsqrtf(s2t*0.0078125f - mean*mean + 1e-6f);
    // pass B: normalize own 32 channels in place
    #pragma unroll
    for (int j = 0; j < 16; ++j) {
        unsigned u = srow[j];
        float v0 = __uint_as_float(u << 16);
        float v1 = __uint_as_float(u & 0xffff0000u);
        const int c = cq*32 + 2*j;
        v0 = (v0 - mean)*rstd*n1w[c]   + n1b[c];
        v1 = (v1 - mean)*rstd*n1w[c+1] + n1b[c+1];
        __hip_bfloat162 pk = __float22bfloat162_rn(make_float2(v0, v1));
        srow[j] = *(unsigned*)&pk;
    }
    __syncthreads();

    float lv[4];
    #pragma unroll
    for (int nt = 0; nt < 4; ++nt)
        lv[nt] = l0[(size_t)b*HW + hw0 + phalf*64 + nt*16 + l15];

    unsigned toff[4];
    #pragma unroll
    for (int nt = 0; nt < 4; ++nt) {
        const int xg = x0 + phalf*64 + nt*16 + l15;
        toff[nt] = (unsigned)((wy*32 + (xg >> 3))*1024 + (ty*8 + (xg & 7))*16);
    }

    const short* wq = (const short*)qkvw;
    for (int oz = 0; oz < 3; ++oz) {
        f32x4 acc[2][4];
        #pragma unroll
        for (int mt = 0; mt < 2; ++mt)
            #pragma unroll
            for (int nt = 0; nt < 4; ++nt)
                acc[mt][nt] = (f32x4){0.f,0.f,0.f,0.f};
        #pragma unroll
        for (int kc = 0; kc < 4; ++kc) {
            bf16x8 bfrag[4];
            #pragma unroll
            for (int nt = 0; nt < 4; ++nt) {
                const int px = phalf*64 + nt*16 + l15;
                bfrag[nt] = *(const bf16x8*)(sxb + px*130 + kc*32 + ko);
            }
            #pragma unroll
            for (int mt = 0; mt < 2; ++mt) {
                const int m = oz*128 + mq*32 + mt*16 + l15;
                bf16x8 af = *(const bf16x8*)(wq + m*128 + kc*32 + ko);
                #pragma unroll
                for (int nt = 0; nt < 4; ++nt)
                    acc[mt][nt] = __builtin_amdgcn_mfma_f32_16x16x32_bf16(af, bfrag[nt], acc[mt][nt], 0, 0, 0);
            }
        }
        __hip_bfloat16* ob = qkvb + (size_t)oz*QKV_OZ + (size_t)b*8*QKV_H;
        #pragma unroll
        for (int mt = 0; mt < 2; ++mt) {
            const int h = mq*2 + mt;
            #pragma unroll
            for (int nt = 0; nt < 4; ++nt) {
                float v0 = acc[mt][nt][0], v1 = acc[mt][nt][1];
                float v2 = acc[mt][nt][2], v3 = acc[mt][nt][3];
                if (oz == 0) {
                    const int o = h*16 + q4;
                    v0 *= sigmoidf_(lv[nt]*gate_w[o]   + gate_b[o]);
                    v1 *= sigmoidf_(lv[nt]*gate_w[o+1] + gate_b[o+1]);
                    v2 *= sigmoidf_(lv[nt]*gate_w[o+2] + gate_b[o+2]);
                    v3 *= sigmoidf_(lv[nt]*gate_w[o+3] + gate_b[o+3]);
                }
                __hip_bfloat162 p0 = __float22bfloat162_rn(make_float2(v0, v1));
                __hip_bfloat162 p1 = __float22bfloat162_rn(make_float2(v2, v3));
                uint2 st;
                st.x = *(unsigned*)&p0;
                st.y = *(unsigned*)&p1;
                *(uint2*)(ob + (size_t)h*QKV_H + toff[nt] + q4) = st;
            }
        }
    }
}

// ---------------- K2: windowed attention, MFMA (token-major bf16 qkv in, f32 out) --------
__global__ __launch_bounds__(256) void k_attn(
    const __hip_bfloat16* __restrict__ qkv, float* __restrict__ attn_out)
{
    __shared__ short vt[4][16*72];            // per-wave V^T: [d][tok], stride 72
    __shared__ short pt[4][64*68];            // per-wave P^T: [i][j], stride 68
    const int t = threadIdx.x;
    const int l = t & 63, w = t >> 6;
    const int c = l & 15, g = l >> 4;
    const int id = blockIdx.x*4 + w;          // b(2) | head(3) | win(10)
    const int b = id >> 13;
    const int head = (id >> 10) & 7;
    const int wi = id & 1023;
    const __hip_bfloat16* qp = qkv + ((size_t)(b*8 + head))*QKV_H + (size_t)wi*QKV_WIN;
    const __hip_bfloat16* kp = qp + QKV_OZ;
    const __hip_bfloat16* vp = qp + 2u*QKV_OZ;

    // stage V^T: lane l owns token l (16 d-values -> 16 scalar LDS writes, 2-way=free)
    bf16x8 v0 = *(const bf16x8*)(vp + l*16);
    bf16x8 v1 = *(const bf16x8*)(vp + l*16 + 8);
    short* vtw = &vt[w][0];
    #pragma unroll
    for (int d = 0; d < 8; ++d) vtw[d*72 + l] = v0[d];
    #pragma unroll
    for (int d = 0; d < 8; ++d) vtw[(8+d)*72 + l] = v1[d];

    // Q/K fragments: lane g<2 holds d-slice g*8..g*8+7 of token (tile*16 + c); g>=2 zero.
    bf16x8 kf[4], qf[4];
    #pragma unroll
    for (int mj = 0; mj < 4; ++mj) {
        if (g < 2) {
            kf[mj] = *(const bf16x8*)(kp + (mj*16 + c)*16 + g*8);
            qf[mj] = *(const bf16x8*)(qp + (mj*16 + c)*16 + g*8);
        } else {
            kf[mj] = (bf16x8){0,0,0,0,0,0,0,0};
            qf[mj] = (bf16x8){0,0,0,0,0,0,0,0};
        }
    }
    // S^T tiles: st[mj][ni]: j = mj*16 + g*4 + r, i = ni*16 + c
    f32x4 st[4][4];
    #pragma unroll
    for (int mj = 0; mj < 4; ++mj)
        #pragma unroll
        for (int ni = 0; ni < 4; ++ni)
            st[mj][ni] = (f32x4){0.f,0.f,0.f,0.f};
    #pragma unroll
    for (int mj = 0; mj < 4; ++mj)
        #pragma unroll
        for (int ni = 0; ni < 4; ++ni)
            st[mj][ni] = __builtin_amdgcn_mfma_f32_16x16x32_bf16(kf[mj], qf[ni], st[mj][ni], 0, 0, 0);

    // softmax over keys j (per query i = ni*16+c); scale 0.25 folded in
    float rs[4];
    bf16x4 pa[4][4], pb[4][4];      // hi/lo bf16 of P^T, [mj][ni]
    #pragma unroll
    for (int ni = 0; ni < 4; ++ni) {
        float mx = -1e30f;
        #pragma unroll
        for (int mj = 0; mj < 4; ++mj)
            #pragma unroll
            for (int r = 0; r < 4; ++r)
                mx = fmaxf(mx, st[mj][ni][r]);
        mx = fmaxf(mx, __shfl_xor(mx, 16));
        mx = fmaxf(mx, __shfl_xor(mx, 32));
        mx *= 0.25f;
        float sum = 0.f;
        #pragma unroll
        for (int mj = 0; mj < 4; ++mj) {
            float p[4], lo[4];
            #pragma unroll
            for (int r = 0; r < 4; ++r) {
                p[r] = __expf(st[mj][ni][r]*0.25f - mx);
                sum += p[r];
            }
            __hip_bfloat162 h0 = __float22bfloat162_rn(make_float2(p[0], p[1]));
            __hip_bfloat162 h1 = __float22bfloat162_rn(make_float2(p[2], p[3]));
            union { unsigned u[2]; bf16x4 v; } hi;
            hi.u[0] = *(unsigned*)&h0; hi.u[1] = *(unsigned*)&h1;
            pa[mj][ni] = hi.v;
            #pragma unroll
            for (int r = 0; r < 4; ++r) lo[r] = p[r] - bf2f(hi.v[r]);
            __hip_bfloat162 g0 = __float22bfloat162_rn(make_float2(lo[0], lo[1]));
            __hip_bfloat162 g1 = __float22bfloat162_rn(make_float2(lo[2], lo[3]));
            union { unsigned u[2]; bf16x4 v; } lw;
            lw.u[0] = *(unsigned*)&g0; lw.u[1] = *(unsigned*)&g1;
            pb[mj][ni] = lw.v;
        }
        sum += __shfl_xor(sum, 16);
        sum += __shfl_xor(sum, 32);
        rs[ni] = 1.f / sum;
    }

    // PV: O^T[d][i] = sum_j V^T[d][j] * P^T[j][i], K=32 x 2 chunks, hi then lo pass.
    short* ptw = &pt[w][0];
    f32x4 oc[4];
    #pragma unroll
    for (int ni = 0; ni < 4; ++ni) oc[ni] = (f32x4){0.f,0.f,0.f,0.f};
    bf16x8 vf[2];
    #pragma unroll
    for (int kb = 0; kb < 2; ++kb)
        vf[kb] = *(const bf16x8*)(vtw + c*72 + kb*32 + g*8);

    // hi pass
    #pragma unroll
    for (int mj = 0; mj < 4; ++mj)
        #pragma unroll
        for (int ni = 0; ni < 4; ++ni)
            *(bf16x4*)(ptw + (ni*16 + c)*68 + mj*16 + g*4) = pa[mj][ni];
    __syncthreads();
    #pragma unroll
    for (int kb = 0; kb < 2; ++kb)
        #pragma unroll
        for (int ni = 0; ni < 4; ++ni) {
            bf16x8 pf = *(const bf16x8*)(ptw + (ni*16 + c)*68 + kb*32 + g*8);
            oc[ni] = __builtin_amdgcn_mfma_f32_16x16x32_bf16(vf[kb], pf, oc[ni], 0, 0, 0);
        }
    __syncthreads();
    // lo pass (reuse buffer)
    #pragma unroll
    for (int mj = 0; mj < 4; ++mj)
        #pragma unroll
        for (int ni = 0; ni < 4; ++ni)
            *(bf16x4*)(ptw + (ni*16 + c)*68 + mj*16 + g*4) = pb[mj][ni];
    __syncthreads();
    #pragma unroll
    for (int kb = 0; kb < 2; ++kb)
        #pragma unroll
        for (int ni = 0; ni < 4; ++ni) {
            bf16x8 pf = *(const bf16x8*)(ptw + (ni*16 + c)*68 + kb*32 + g*8);
            oc[ni] = __builtin_amdgcn_mfma_f32_16x16x32_bf16(vf[kb], pf, oc[ni], 0, 0, 0);
        }

    const int wy = wi >> 5, wx = wi & 31;
    float* ob = attn_out + (size_t)b*CHW + (size_t)(head*16)*HW + (size_t)(wy*8)*256 + wx*8;
    #pragma unroll
    for (int ni = 0; ni < 4; ++ni) {
        const int tok = ni*16 + c;
        float* o2 = ob + (tok >> 3)*256 + (tok & 7);
        #pragma unroll
        for (int r = 0; r < 4; ++r) {
            const int d = g*4 + r;
            o2[(size_t)d*HW] = oc[ni][r] * rs[ni];
        }
    }
}

// ---------------- K3: proj (MFMA) + bias + shortcut, in-place on d_out ----------------
__global__ __launch_bounds__(256,3) void k_proj_mfma(
    const float* __restrict__ x, const __hip_bfloat16* __restrict__ projw,
    const float* __restrict__ proj_b, float* __restrict__ out)
{
    __shared__ short sxb[128*130];
    const int t = threadIdx.x;
    const int lane = t & 63, w = t >> 6;
    const int l15 = lane & 15, q4 = (lane >> 4)*4, ko = (lane >> 4)*8;
    const int mhalf = w & 1, phalf = w >> 1;
    const int pbase = blockIdx.x * 128;
    const int b = pbase >> 16;
    const int hw0 = pbase & 65535;
    const int pxs = t & 127, chalf = t >> 7;
    const float* ab = out + (size_t)b*CHW + (size_t)chalf*64*HW + hw0 + pxs;
    unsigned* srow = (unsigned*)sxb + pxs*65 + chalf*32;
    #pragma unroll 8
    for (int j = 0; j < 32; ++j) {
        float v0 = ab[(size_t)(2*j)*HW];
        float v1 = ab[(size_t)(2*j+1)*HW];
        __hip_bfloat162 pk = __float22bfloat162_rn(make_float2(v0, v1));
        srow[j] = *(unsigned*)&pk;
    }
    __syncthreads();
    f32x4 acc[4][4];
    #pragma unroll
    for (int mt = 0; mt < 4; ++mt)
        #pragma unroll
        for (int nt = 0; nt < 4; ++nt)
            acc[mt][nt] = (f32x4){0.f,0.f,0.f,0.f};
    const short* wp = (const short*)projw;
    #pragma unroll
    for (int kc = 0; kc < 4; ++kc) {
        bf16x8 bfrag[4];
        #pragma unroll
        for (int nt = 0; nt < 4; ++nt) {
            const int px = phalf*64 + nt*16 + l15;
            bfrag[nt] = *(const bf16x8*)(sxb + px*130 + kc*32 + ko);
        }
        #pragma unroll
        for (int mt = 0; mt < 4; ++mt) {
            const int m = mhalf*64 + mt*16 + l15;
            bf16x8 af = *(const bf16x8*)(wp + m*128 + kc*32 + ko);
            #pragma unroll
            for (int nt = 0; nt < 4; ++nt)
                acc[mt][nt] = __builtin_amdgcn_mfma_f32_16x16x32_bf16(af, bfrag[nt], acc[mt][nt], 0, 0, 0);
        }
    }
    const float* xb = x + (size_t)b*CHW + hw0;
    float* ob = out + (size_t)b*CHW + hw0;
    #pragma unroll
    for (int mt = 0; mt < 4; ++mt)
        #pragma unroll
        for (int nt = 0; nt < 4; ++nt) {
            const int px = phalf*64 + nt*16 + l15;
            #pragma unroll
            for (int r = 0; r < 4; ++r) {
                const int o = mhalf*64 + mt*16 + q4 + r;
                ob[(size_t)o*HW + px] = acc[mt][nt][r] + proj_b[o] + xb[(size_t)o*HW + px];
            }
        }
}

// ---------------- K4: LN2 + FFN1 (MFMA) + bias + GELU -> h1 bf16 (PER BATCH) ----------------
__global__ __launch_bounds__(256,3) void k_ffn1_mfma(
    const float* __restrict__ outb, const float* __restrict__ n2w, const float* __restrict__ n2b,
    const __hip_bfloat16* __restrict__ w1, const float* __restrict__ b1,
    __hip_bfloat16* __restrict__ h1s)
{
    __shared__ short sxb[128*130];
    __shared__ float sp1[256], sp2[256];
    const int t = threadIdx.x;
    const int lane = t & 63, w = t >> 6;
    const int l15 = lane & 15, q4 = (lane >> 4)*4, ko = (lane >> 4)*8;
    const int mhalf = w & 1, phalf = w >> 1;
    const int hw0 = blockIdx.x * 128;
    const int pxs = t & 127, chalf = t >> 7;
    const float* xb = outb + (size_t)chalf*64*HW + hw0 + pxs;
    unsigned* srow = (unsigned*)sxb + pxs*65 + chalf*32;
    float s1 = 0.f, s2 = 0.f;
    #pragma unroll 8
    for (int j = 0; j < 32; ++j) {
        float v0 = xb[(size_t)(2*j)*HW];
        float v1 = xb[(size_t)(2*j+1)*HW];
        s1 += v0 + v1; s2 += v0*v0 + v1*v1;
        __hip_bfloat162 pk = __float22bfloat162_rn(make_float2(v0, v1));
        srow[j] = *(unsigned*)&pk;
    }
    sp1[pxs*2 + chalf] = s1;
    sp2[pxs*2 + chalf] = s2;
    __syncthreads();
    const float s1t = sp1[pxs*2] + sp1[pxs*2 + 1];
    const float s2t = sp2[pxs*2] + sp2[pxs*2 + 1];
    const float mean = s1t * 0.0078125f;
    const float rstd = rsqrtf(s2t*0.0078125f - mean*mean + 1e-6f);
    #pragma unroll 8
    for (int j = 0; j < 32; ++j) {
        unsigned u = srow[j];
        float v0 = __uint_as_float(u << 16);
        float v1 = __uint_as_float(u & 0xffff0000u);
        const int c = chalf*64 + 2*j;
        v0 = (v0 - mean)*rstd*n2w[c]   + n2b[c];
        v1 = (v1 - mean)*rstd*n2w[c+1] + n2b[c+1];
        __hip_bfloat162 pk = __float22bfloat162_rn(make_float2(v0, v1));
        srow[j] = *(unsigned*)&pk;
    }
    __syncthreads();
    const short* w1s = (const short*)w1;
    __hip_bfloat16* hb = h1s + hw0;
    for (int mc = 0; mc < 4; ++mc) {
        f32x4 acc[4][4];
        #pragma unroll
        for (int mt = 0; mt < 4; ++mt)
            #pragma unroll
            for (int nt = 0; nt < 4; ++nt)
                acc[mt][nt] = (f32x4){0.f,0.f,0.f,0.f};
        #pragma unroll
        for (int kc = 0; kc < 4; ++kc) {
            bf16x8 bfrag[4];
            #pragma unroll
            for (int nt = 0; nt < 4; ++nt) {
                const int px = phalf*64 + nt*16 + l15;
                bfrag[nt] = *(const bf16x8*)(sxb + px*130 + kc*32 + ko);
            }
            #pragma unroll
            for (int mt = 0; mt < 4; ++mt) {
                const int m = mc*128 + mhalf*64 + mt*16 + l15;
                bf16x8 af = *(const bf16x8*)(w1s + m*128 + kc*32 + ko);
                #pragma unroll
                for (int nt = 0; nt < 4; ++nt)
                    acc[mt][nt] = __builtin_amdgcn_mfma_f32_16x16x32_bf16(af, bfrag[nt], acc[mt][nt], 0, 0, 0);
            }
        }
        #pragma unroll
        for (int mt = 0; mt < 4; ++mt)
            #pragma unroll
            for (int nt = 0; nt < 4; ++nt) {
                const int px = phalf*64 + nt*16 + l15;
                #pragma unroll
                for (int r = 0; r < 4; ++r) {
                    const int o = mc*128 + mhalf*64 + mt*16 + q4 + r;
                    const float v = geluf(acc[mt][nt][r] + b1[o]);
                    hb[(size_t)o*HW + px] = __float2bfloat16(v);
                }
            }
    }
}

// ---------------- K5a: depthwise 3x3 + GELU on channel PAIRS -> h2 (pair-interleaved bf16) ----
__global__ __launch_bounds__(256) void k_dwconv(
    const __hip_bfloat16* __restrict__ h1b,   // batch base: [512][HW] bf16
    unsigned* __restrict__ h2u,               // [256][HW] pair-packed
    const float* __restrict__ dwf, const float* __restrict__ dwb)
{
    __shared__ short sh[2*18*260];            // 2 ch x 18 rows x (2 + 256 + 1 + pad) cols
    const int t = threadIdx.x;
    const int rb = blockIdx.x & 15;
    const int cp = blockIdx.x >> 4;           // channel pair 0..255
    const int row0 = rb * 16;
    #pragma unroll
    for (int ch = 0; ch < 2; ++ch) {
        const __hip_bfloat16* src = h1b + (size_t)(cp*2 + ch)*HW;
        #pragma unroll
        for (int i = 0; i < 9; ++i) {
            const int idx = t + i*256;
            const int r = idx >> 7;           // 0..17
            const int u = idx & 127;          // uint col (2 pixels)
            const int y = row0 - 1 + r;
            unsigned v = 0u;
            if ((unsigned)y < 256u) v = *(const unsigned*)(src + (size_t)y*256 + u*2);
            *(unsigned*)(&sh[ch*4680 + r*260 + 2 + u*2]) = v;
        }
    }
    if (t < 72) {
        const int ch = t / 36, q = t - ch*36;
        const int r = q >> 1;
        sh[ch*4680 + r*260 + ((q & 1) ? 258 : 1)] = 0;
    }
    __syncthreads();
    float wt[2][9], bs[2];
    #pragma unroll
    for (int ch = 0; ch < 2; ++ch) {
        const float* dwc = dwf + (size_t)(cp*2 + ch)*9;
        #pragma unroll
        for (int k = 0; k < 9; ++k) wt[ch][k] = dwc[k];
        bs[ch] = dwb[cp*2 + ch];
    }
    const int xp = (t & 127) * 2;   // this thread's output column pair
    const int rh = t >> 7;          // row half (8 rows each)
    #pragma unroll
    for (int r = 0; r < 8; ++r) {
        const int orow = rh*8 + r;            // 0..15 within block
        const int y = row0 + orow;
        float res[2][2];
        #pragma unroll
        for (int ch = 0; ch < 2; ++ch) {
            const short* base = sh + ch*4680 + orow*260 + xp + 1;
            float a[3][4];
            #pragma unroll
            for (int dy = 0; dy < 3; ++dy)
                #pragma unroll
                for (int k = 0; k < 4; ++k)
                    a[dy][k] = __uint_as_float((unsigned)(unsigned short)base[dy*260 + k] << 16);
            #pragma unroll
            for (int xj = 0; xj < 2; ++xj) {
                float s = bs[ch];
                #pragma unroll
                for (int dy = 0; dy < 3; ++dy)
                    #pragma unroll
                    for (int dx = 0; dx < 3; ++dx)
                        s = fmaf(a[dy][xj+dx], wt[ch][dy*3+dx], s);
                res[ch][xj] = geluf(s);
            }
        }
        __hip_bfloat162 pk0 = __float22bfloat162_rn(make_float2(res[0][0], res[1][0]));
        __hip_bfloat162 pk1 = __float22bfloat162_rn(make_float2(res[0][1], res[1][1]));
        uint2 st;
        st.x = *(unsigned*)&pk0;
        st.y = *(unsigned*)&pk1;
        *(uint2*)(h2u + (size_t)cp*HW + (size_t)y*256 + xp) = st;
    }
}

// ---------------- K5b: FFN2 GEMM (128 out x 512 in) + bias + residual, per batch ----------------
__global__ __launch_bounds__(256,3) void k_ffn2g(
    const unsigned* __restrict__ h2u, const __hip_bfloat16* __restrict__ w2b,
    const float* __restrict__ b2, float* __restrict__ outb)
{
    __shared__ short sxb[128*130];            // [px][128 ch + 2 pad]
    const int t = threadIdx.x;
    const int lane = t & 63, w = t >> 6;
    const int l15 = lane & 15, q4 = (lane >> 4)*4, ko = (lane >> 4)*8;
    const int mhalf = w & 1, phalf = w >> 1;
    const int pbase = blockIdx.x * 128;
    const int pxs = t & 127;                  // staging: this thread's pixel row
    const int chalf = t >> 7;                 // staging: channel-pair half
    f32x4 acc[4][4];
    #pragma unroll
    for (int mt = 0; mt < 4; ++mt)
        #pragma unroll
        for (int nt = 0; nt < 4; ++nt)
            acc[mt][nt] = (f32x4){0.f,0.f,0.f,0.f};
    const short* w2s = (const short*)w2b;
    for (int k4 = 0; k4 < 4; ++k4) {
        if (k4) __syncthreads();
        const unsigned* hsrc = h2u + (size_t)(k4*64 + chalf*32)*HW + pbase + pxs;
        unsigned* sdst = (unsigned*)sxb + pxs*65 + chalf*32;
        #pragma unroll
        for (int c = 0; c < 32; ++c)
            sdst[c] = hsrc[(size_t)c*HW];
        __syncthreads();
        #pragma unroll
        for (int kc = 0; kc < 4; ++kc) {
            bf16x8 bfrag[4];
            #pragma unroll
            for (int nt = 0; nt < 4; ++nt) {
                const int px = phalf*64 + nt*16 + l15;
                bfrag[nt] = *(const bf16x8*)(sxb + px*130 + kc*32 + ko);
            }
            #pragma unroll
            for (int mt = 0; mt < 4; ++mt) {
                const int m = mhalf*64 + mt*16 + l15;
                bf16x8 af = *(const bf16x8*)(w2s + (size_t)m*512 + k4*128 + kc*32 + ko);
                #pragma unroll
                for (int nt = 0; nt < 4; ++nt)
                    acc[mt][nt] = __builtin_amdgcn_mfma_f32_16x16x32_bf16(af, bfrag[nt], acc[mt][nt], 0, 0, 0);
            }
        }
    }
    #pragma unroll
    for (int mt = 0; mt < 4; ++mt)
        #pragma unroll
        for (int nt = 0; nt < 4; ++nt) {
            const int px = pbase + phalf*64 + nt*16 + l15;
            #pragma unroll
            for (int r = 0; r < 4; ++r) {
                const int o = mhalf*64 + mt*16 + q4 + r;
                outb[(size_t)o*HW + px] = acc[mt][nt][r] + b2[o] + outb[(size_t)o*HW + px];
            }
        }
}

extern "C" void kernel_launch(void* const* d_in, const int* in_sizes, int n_in,
                              void* d_out, int out_size, void* d_ws, size_t ws_size,
                              hipStream_t stream) {
    const float* x      = (const float*)d_in[0];
    const float* l0     = (const float*)d_in[1];
    const float* n1w    = (const float*)d_in[2];
    const float* n1b    = (const float*)d_in[3];
    const float* n2w    = (const float*)d_in[4];
    const float* n2b    = (const float*)d_in[5];
    const float* qkv_w  = (const float*)d_in[6];
    const float* gate_w = (const float*)d_in[7];
    const float* gate_b = (const float*)d_in[8];
    const float* proj_w = (const float*)d_in[9];
    const float* proj_b = (const float*)d_in[10];
    const float* ffn_w1 = (const float*)d_in[11];
    const float* ffn_b1 = (const float*)d_in[12];
    const float* ffn_dw = (const float*)d_in[13];
    const float* ffn_dwb= (const float*)d_in[14];
    const float* ffn_w2 = (const float*)d_in[15];
    const float* ffn_b2 = (const float*)d_in[16];

    float* out = (float*)d_out;
    // ws layout (max byte touched = 268,828,672 — identical to the proven footprint):
    //   [0,192 MiB)        qkv bf16 token-major (dead after attn; first 64 MiB reused as h2u)
    //   [192,256 MiB)      h1 per-batch slot (64 MiB)
    //   [256 MiB,+384 KiB) bf16 weights
    __hip_bfloat16* qkvb = (__hip_bfloat16*)d_ws;
    unsigned* h2u        = (unsigned*)d_ws;                              // aliases dead qkv
    __hip_bfloat16* h1s  = (__hip_bfloat16*)((char*)d_ws + 201326592);   // 192 MiB
    char* wbase = (char*)d_ws + 268435456;
    __hip_bfloat16* qkvw_b = (__hip_bfloat16*)(wbase);
    __hip_bfloat16* projw_b= (__hip_bfloat16*)(wbase + 98304);
    __hip_bfloat16* w1b    = (__hip_bfloat16*)(wbase + 131072);
    __hip_bfloat16* w2b    = (__hip_bfloat16*)(wbase + 262144);

    k_cvt<<<dim3(192), dim3(256), 0, stream>>>(qkv_w, qkvw_b, 49152);
    k_cvt<<<dim3(64),  dim3(256), 0, stream>>>(proj_w, projw_b, 16384);
    k_cvt<<<dim3(256), dim3(256), 0, stream>>>(ffn_w1, w1b, 65536);
    k_cvt<<<dim3(256), dim3(256), 0, stream>>>(ffn_w2, w2b, 65536);

    k_ln_qkv_mfma<<<dim3(2048), dim3(512), 0, stream>>>(x, l0, n1w, n1b, qkvw_b, gate_w, gate_b, qkvb);
    k_attn       <<<dim3(8192), dim3(256), 0, stream>>>(qkvb, out);
    k_proj_mfma  <<<dim3(2048), dim3(256), 0, stream>>>(x, projw_b, proj_b, out);
    for (int b = 0; b < 4; ++b) {
        k_ffn1_mfma<<<dim3(512),  dim3(256), 0, stream>>>(out + (size_t)b*CHW, n2w, n2b, w1b, ffn_b1, h1s);
        k_dwconv   <<<dim3(4096), dim3(256), 0, stream>>>(h1s, h2u, ffn_dw, ffn_dwb);
        k_ffn2g    <<<dim3(512),  dim3(256), 0, stream>>>(h2u, w2b, ffn_b2, out + (size_t)b*CHW);
    }
}

// Round 9
// 1086.007 us; speedup vs baseline: 1.0538x; 1.0293x over previous
//
#include <hip/hip_runtime.h>
#include <hip/hip_bf16.h>

#define HW   65536
#define CHW  (128*65536)
// token-major qkv: [oz][b][head][win][tok][d] bf16; strides in elements:
#define QKV_OZ  33554432u   // 4*8*1024*64*16
#define QKV_H   1048576u    // 1024*64*16
#define QKV_WIN 1024u       // 64*16

typedef __attribute__((ext_vector_type(8))) short bf16x8;
typedef __attribute__((ext_vector_type(4))) short bf16x4;
typedef __attribute__((ext_vector_type(4))) float f32x4;

__device__ __forceinline__ float geluf(float v){
    // tanh-form GELU, overflow-safe. max abs dev from exact erf-GELU ~1e-3.
    float u = 0.7978845608028654f * v * (1.f + 0.044715f*v*v);
    float e = __expf(2.f*u);
    float th = 1.f - 2.f/(e+1.f);
    return 0.5f*v*(1.f+th);
}

__device__ __forceinline__ float sigmoidf_(float z){
    return 1.f / (1.f + __expf(-z));
}

__device__ __forceinline__ float bf2f(short s){
    return __uint_as_float(((unsigned)(unsigned short)s) << 16);
}

// ---------------- K0: f32 -> bf16 weight conversion ----------------
__global__ __launch_bounds__(256) void k_cvt(
    const float* __restrict__ src, __hip_bfloat16* __restrict__ dst, int n)
{
    int i = blockIdx.x*256 + threadIdx.x;
    if (i < n) dst[i] = __float2bfloat16(src[i]);
}

// ---------------- K1: LN1 + QKV GEMM (MFMA) + gate(q) -> qkv bf16 (token-major) ----------------
// 512 threads / 8 waves; waves split M(4) x px(2): acc[2][4] = 32 regs/wave.
// sp1/sp2 laid out [cq*128+pxs]: stride-1 writes (bank-conflict-free; was 8-way).
__global__ __launch_bounds__(512,2) void k_ln_qkv_mfma(
    const float* __restrict__ x, const float* __restrict__ l0,
    const float* __restrict__ n1w, const float* __restrict__ n1b,
    const __hip_bfloat16* __restrict__ qkvw, const float* __restrict__ gate_w,
    const float* __restrict__ gate_b, __hip_bfloat16* __restrict__ qkvb)
{
    __shared__ short sxb[128*130];      // [px][128 bf16 + 2 pad] = 65 dwords/row, odd -> conflict-free
    __shared__ float sp1[512], sp2[512];
    const int t = threadIdx.x;
    const int lane = t & 63, w = t >> 6;           // 8 waves
    const int l15 = lane & 15, q4 = (lane >> 4)*4, ko = (lane >> 4)*8;
    const int mq = w & 3, phalf = w >> 2;          // M quarter (32 rows), px half (64 px)
    const int pbase = blockIdx.x * 128;
    const int b = pbase >> 16;
    const int hw0 = pbase & 65535;
    const int x0 = hw0 & 255;           // 0 or 128 (tile stays in one image row)
    const int y  = hw0 >> 8;
    const int wy = y >> 3, ty = y & 7;
    const int pxs = t & 127, cq = t >> 7;          // 4 threads per pixel, 32 channels each
    const float* xb = x + (size_t)b*CHW + (size_t)cq*32*HW + hw0 + pxs;
    unsigned* srow = (unsigned*)sxb + pxs*65 + cq*16;

    // pass A: partial LN stats + raw bf16 stash (32 channels per thread)
    float s1 = 0.f, s2 = 0.f;
    #pragma unroll
    for (int j = 0; j < 16; ++j) {
        float v0 = xb[(size_t)(2*j)*HW];
        float v1 = xb[(size_t)(2*j+1)*HW];
        s1 += v0 + v1; s2 += v0*v0 + v1*v1;
        __hip_bfloat162 pk = __float22bfloat162_rn(make_float2(v0, v1));
        srow[j] = *(unsigned*)&pk;
    }
    sp1[cq*128 + pxs] = s1;
    sp2[cq*128 + pxs] = s2;
    __syncthreads();
    const float s1t = sp1[pxs] + sp1[128+pxs] + sp1[256+pxs] + sp1[384+pxs];
    const float s2t = sp2[pxs] + sp2[128+pxs] + sp2[256+pxs] + sp2[384+pxs];
    const float mean = s1t * 0.0078125f;
    const float rstd = rsqrtf(s2t*0.0078125f - mean*mean + 1e-6f);
    // pass B: normalize own 32 channels in place
    #pragma unroll
    for (int j = 0; j < 16; ++j) {
        unsigned u = srow[j];
        float v0 = __uint_as_float(u << 16);
        float v1 = __uint_as_float(u & 0xffff0000u);
        const int c = cq*32 + 2*j;
        v0 = (v0 - mean)*rstd*n1w[c]   + n1b[c];
        v1 = (v1 - mean)*rstd*n1w[c+1] + n1b[c+1];
        __hip_bfloat162 pk = __float22bfloat162_rn(make_float2(v0, v1));
        srow[j] = *(unsigned*)&pk;
    }
    __syncthreads();

    float lv[4];
    #pragma unroll
    for (int nt = 0; nt < 4; ++nt)
        lv[nt] = l0[(size_t)b*HW + hw0 + phalf*64 + nt*16 + l15];

    unsigned toff[4];
    #pragma unroll
    for (int nt = 0; nt < 4; ++nt) {
        const int xg = x0 + phalf*64 + nt*16 + l15;
        toff[nt] = (unsigned)((wy*32 + (xg >> 3))*1024 + (ty*8 + (xg & 7))*16);
    }

    const short* wq = (const short*)qkvw;
    for (int oz = 0; oz < 3; ++oz) {
        f32x4 acc[2][4];
        #pragma unroll
        for (int mt = 0; mt < 2; ++mt)
            #pragma unroll
            for (int nt = 0; nt < 4; ++nt)
                acc[mt][nt] = (f32x4){0.f,0.f,0.f,0.f};
        #pragma unroll
        for (int kc = 0; kc < 4; ++kc) {
            bf16x8 bfrag[4];
            #pragma unroll
            for (int nt = 0; nt < 4; ++nt) {
                const int px = phalf*64 + nt*16 + l15;
                bfrag[nt] = *(const bf16x8*)(sxb + px*130 + kc*32 + ko);
            }
            #pragma unroll
            for (int mt = 0; mt < 2; ++mt) {
                const int m = oz*128 + mq*32 + mt*16 + l15;
                bf16x8 af = *(const bf16x8*)(wq + m*128 + kc*32 + ko);
                #pragma unroll
                for (int nt = 0; nt < 4; ++nt)
                    acc[mt][nt] = __builtin_amdgcn_mfma_f32_16x16x32_bf16(af, bfrag[nt], acc[mt][nt], 0, 0, 0);
            }
        }
        __hip_bfloat16* ob = qkvb + (size_t)oz*QKV_OZ + (size_t)b*8*QKV_H;
        #pragma unroll
        for (int mt = 0; mt < 2; ++mt) {
            const int h = mq*2 + mt;
            #pragma unroll
            for (int nt = 0; nt < 4; ++nt) {
                float v0 = acc[mt][nt][0], v1 = acc[mt][nt][1];
                float v2 = acc[mt][nt][2], v3 = acc[mt][nt][3];
                if (oz == 0) {
                    const int o = h*16 + q4;
                    v0 *= sigmoidf_(lv[nt]*gate_w[o]   + gate_b[o]);
                    v1 *= sigmoidf_(lv[nt]*gate_w[o+1] + gate_b[o+1]);
                    v2 *= sigmoidf_(lv[nt]*gate_w[o+2] + gate_b[o+2]);
                    v3 *= sigmoidf_(lv[nt]*gate_w[o+3] + gate_b[o+3]);
                }
                __hip_bfloat162 p0 = __float22bfloat162_rn(make_float2(v0, v1));
                __hip_bfloat162 p1 = __float22bfloat162_rn(make_float2(v2, v3));
                uint2 st;
                st.x = *(unsigned*)&p0;
                st.y = *(unsigned*)&p1;
                *(uint2*)(ob + (size_t)h*QKV_H + toff[nt] + q4) = st;
            }
        }
    }
}

// ---------------- K2: windowed attention, MFMA -> bf16 pair-packed output --------
// Output apack: uint[b][64 pair-rows][HW], uint = (bf16 ch(2p) | bf16 ch(2p+1)<<16).
// Rounding point identical to old proj staging -> same numerics, half the bytes.
__global__ __launch_bounds__(256) void k_attn(
    const __hip_bfloat16* __restrict__ qkv, unsigned* __restrict__ apack)
{
    __shared__ short vt[4][16*72];            // per-wave V^T: [d][tok], stride 72
    __shared__ short pt[4][64*68];            // per-wave P^T: [i][j], stride 68
    const int t = threadIdx.x;
    const int l = t & 63, w = t >> 6;
    const int c = l & 15, g = l >> 4;
    const int id = blockIdx.x*4 + w;          // b(2) | head(3) | win(10)
    const int b = id >> 13;
    const int head = (id >> 10) & 7;
    const int wi = id & 1023;
    const __hip_bfloat16* qp = qkv + ((size_t)(b*8 + head))*QKV_H + (size_t)wi*QKV_WIN;
    const __hip_bfloat16* kp = qp + QKV_OZ;
    const __hip_bfloat16* vp = qp + 2u*QKV_OZ;

    // stage V^T: lane l owns token l (16 d-values -> 16 scalar LDS writes, 2-way=free)
    bf16x8 v0 = *(const bf16x8*)(vp + l*16);
    bf16x8 v1 = *(const bf16x8*)(vp + l*16 + 8);
    short* vtw = &vt[w][0];
    #pragma unroll
    for (int d = 0; d < 8; ++d) vtw[d*72 + l] = v0[d];
    #pragma unroll
    for (int d = 0; d < 8; ++d) vtw[(8+d)*72 + l] = v1[d];

    // Q/K fragments: lane g<2 holds d-slice g*8..g*8+7 of token (tile*16 + c); g>=2 zero.
    bf16x8 kf[4], qf[4];
    #pragma unroll
    for (int mj = 0; mj < 4; ++mj) {
        if (g < 2) {
            kf[mj] = *(const bf16x8*)(kp + (mj*16 + c)*16 + g*8);
            qf[mj] = *(const bf16x8*)(qp + (mj*16 + c)*16 + g*8);
        } else {
            kf[mj] = (bf16x8){0,0,0,0,0,0,0,0};
            qf[mj] = (bf16x8){0,0,0,0,0,0,0,0};
        }
    }
    // S^T tiles: st[mj][ni]: j = mj*16 + g*4 + r, i = ni*16 + c
    f32x4 st[4][4];
    #pragma unroll
    for (int mj = 0; mj < 4; ++mj)
        #pragma unroll
        for (int ni = 0; ni < 4; ++ni)
            st[mj][ni] = (f32x4){0.f,0.f,0.f,0.f};
    #pragma unroll
    for (int mj = 0; mj < 4; ++mj)
        #pragma unroll
        for (int ni = 0; ni < 4; ++ni)
            st[mj][ni] = __builtin_amdgcn_mfma_f32_16x16x32_bf16(kf[mj], qf[ni], st[mj][ni], 0, 0, 0);

    // softmax over keys j (per query i = ni*16+c); scale 0.25 folded in
    float rs[4];
    bf16x4 pa[4][4], pb[4][4];      // hi/lo bf16 of P^T, [mj][ni]
    #pragma unroll
    for (int ni = 0; ni < 4; ++ni) {
        float mx = -1e30f;
        #pragma unroll
        for (int mj = 0; mj < 4; ++mj)
            #pragma unroll
            for (int r = 0; r < 4; ++r)
                mx = fmaxf(mx, st[mj][ni][r]);
        mx = fmaxf(mx, __shfl_xor(mx, 16));
        mx = fmaxf(mx, __shfl_xor(mx, 32));
        mx *= 0.25f;
        float sum = 0.f;
        #pragma unroll
        for (int mj = 0; mj < 4; ++mj) {
            float p[4], lo[4];
            #pragma unroll
            for (int r = 0; r < 4; ++r) {
                p[r] = __expf(st[mj][ni][r]*0.25f - mx);
                sum += p[r];
            }
            __hip_bfloat162 h0 = __float22bfloat162_rn(make_float2(p[0], p[1]));
            __hip_bfloat162 h1 = __float22bfloat162_rn(make_float2(p[2], p[3]));
            union { unsigned u[2]; bf16x4 v; } hi;
            hi.u[0] = *(unsigned*)&h0; hi.u[1] = *(unsigned*)&h1;
            pa[mj][ni] = hi.v;
            #pragma unroll
            for (int r = 0; r < 4; ++r) lo[r] = p[r] - bf2f(hi.v[r]);
            __hip_bfloat162 g0 = __float22bfloat162_rn(make_float2(lo[0], lo[1]));
            __hip_bfloat162 g1 = __float22bfloat162_rn(make_float2(lo[2], lo[3]));
            union { unsigned u[2]; bf16x4 v; } lw;
            lw.u[0] = *(unsigned*)&g0; lw.u[1] = *(unsigned*)&g1;
            pb[mj][ni] = lw.v;
        }
        sum += __shfl_xor(sum, 16);
        sum += __shfl_xor(sum, 32);
        rs[ni] = 1.f / sum;
    }

    // PV: O^T[d][i] = sum_j V^T[d][j] * P^T[j][i], K=32 x 2 chunks, hi then lo pass.
    short* ptw = &pt[w][0];
    f32x4 oc[4];
    #pragma unroll
    for (int ni = 0; ni < 4; ++ni) oc[ni] = (f32x4){0.f,0.f,0.f,0.f};
    bf16x8 vf[2];
    #pragma unroll
    for (int kb = 0; kb < 2; ++kb)
        vf[kb] = *(const bf16x8*)(vtw + c*72 + kb*32 + g*8);

    // hi pass
    #pragma unroll
    for (int mj = 0; mj < 4; ++mj)
        #pragma unroll
        for (int ni = 0; ni < 4; ++ni)
            *(bf16x4*)(ptw + (ni*16 + c)*68 + mj*16 + g*4) = pa[mj][ni];
    __syncthreads();
    #pragma unroll
    for (int kb = 0; kb < 2; ++kb)
        #pragma unroll
        for (int ni = 0; ni < 4; ++ni) {
            bf16x8 pf = *(const bf16x8*)(ptw + (ni*16 + c)*68 + kb*32 + g*8);
            oc[ni] = __builtin_amdgcn_mfma_f32_16x16x32_bf16(vf[kb], pf, oc[ni], 0, 0, 0);
        }
    __syncthreads();
    // lo pass (reuse buffer)
    #pragma unroll
    for (int mj = 0; mj < 4; ++mj)
        #pragma unroll
        for (int ni = 0; ni < 4; ++ni)
            *(bf16x4*)(ptw + (ni*16 + c)*68 + mj*16 + g*4) = pb[mj][ni];
    __syncthreads();
    #pragma unroll
    for (int kb = 0; kb < 2; ++kb)
        #pragma unroll
        for (int ni = 0; ni < 4; ++ni) {
            bf16x8 pf = *(const bf16x8*)(ptw + (ni*16 + c)*68 + kb*32 + g*8);
            oc[ni] = __builtin_amdgcn_mfma_f32_16x16x32_bf16(vf[kb], pf, oc[ni], 0, 0, 0);
        }

    const int wy = wi >> 5, wx = wi & 31;
    // pair-rows: channels (2p,2p+1); d=g*4+r -> rows head*8+g*2 (r=0,1) and +1 (r=2,3)
    unsigned* ob = apack + (size_t)b*64*HW + (size_t)(head*8 + g*2)*HW
                 + (size_t)(wy*8)*256 + wx*8;
    #pragma unroll
    for (int ni = 0; ni < 4; ++ni) {
        const int tok = ni*16 + c;
        const int hw = (tok >> 3)*256 + (tok & 7);
        __hip_bfloat162 p0 = __float22bfloat162_rn(make_float2(oc[ni][0]*rs[ni], oc[ni][1]*rs[ni]));
        __hip_bfloat162 p1 = __float22bfloat162_rn(make_float2(oc[ni][2]*rs[ni], oc[ni][3]*rs[ni]));
        ob[hw]            = *(unsigned*)&p0;
        ob[(size_t)HW+hw] = *(unsigned*)&p1;
    }
}

// ---------------- K3: proj (MFMA) + bias + shortcut -> out (f32) ----------------
// Stages from pair-packed bf16 apack (uint loads, no conversion).
__global__ __launch_bounds__(256,3) void k_proj_mfma(
    const float* __restrict__ x, const unsigned* __restrict__ apack,
    const __hip_bfloat16* __restrict__ projw,
    const float* __restrict__ proj_b, float* __restrict__ out)
{
    __shared__ short sxb[128*130];
    const int t = threadIdx.x;
    const int lane = t & 63, w = t >> 6;
    const int l15 = lane & 15, q4 = (lane >> 4)*4, ko = (lane >> 4)*8;
    const int mhalf = w & 1, phalf = w >> 1;
    const int pbase = blockIdx.x * 128;
    const int b = pbase >> 16;
    const int hw0 = pbase & 65535;
    const int pxs = t & 127, chalf = t >> 7;
    const unsigned* hsrc = apack + (size_t)b*64*HW + (size_t)chalf*32*HW + hw0 + pxs;
    unsigned* sdst = (unsigned*)sxb + pxs*65 + chalf*32;
    #pragma unroll
    for (int c = 0; c < 32; ++c)
        sdst[c] = hsrc[(size_t)c*HW];
    __syncthreads();
    f32x4 acc[4][4];
    #pragma unroll
    for (int mt = 0; mt < 4; ++mt)
        #pragma unroll
        for (int nt = 0; nt < 4; ++nt)
            acc[mt][nt] = (f32x4){0.f,0.f,0.f,0.f};
    const short* wp = (const short*)projw;
    #pragma unroll
    for (int kc = 0; kc < 4; ++kc) {
        bf16x8 bfrag[4];
        #pragma unroll
        for (int nt = 0; nt < 4; ++nt) {
            const int px = phalf*64 + nt*16 + l15;
            bfrag[nt] = *(const bf16x8*)(sxb + px*130 + kc*32 + ko);
        }
        #pragma unroll
        for (int mt = 0; mt < 4; ++mt) {
            const int m = mhalf*64 + mt*16 + l15;
            bf16x8 af = *(const bf16x8*)(wp + m*128 + kc*32 + ko);
            #pragma unroll
            for (int nt = 0; nt < 4; ++nt)
                acc[mt][nt] = __builtin_amdgcn_mfma_f32_16x16x32_bf16(af, bfrag[nt], acc[mt][nt], 0, 0, 0);
        }
    }
    const float* xb = x + (size_t)b*CHW + hw0;
    float* ob = out + (size_t)b*CHW + hw0;
    #pragma unroll
    for (int mt = 0; mt < 4; ++mt)
        #pragma unroll
        for (int nt = 0; nt < 4; ++nt) {
            const int px = phalf*64 + nt*16 + l15;
            #pragma unroll
            for (int r = 0; r < 4; ++r) {
                const int o = mhalf*64 + mt*16 + q4 + r;
                ob[(size_t)o*HW + px] = acc[mt][nt][r] + proj_b[o] + xb[(size_t)o*HW + px];
            }
        }
}

// ---------------- K4: LN2 + FFN1 (MFMA) + bias + GELU -> h1 bf16 (2-batch grid) ----------------
// grid 1024 covers 2 batches; outb2 = out + b2*2*CHW; h1s has 2 x 64MiB slabs.
__global__ __launch_bounds__(256,3) void k_ffn1_mfma(
    const float* __restrict__ outb2, const float* __restrict__ n2w, const float* __restrict__ n2b,
    const __hip_bfloat16* __restrict__ w1, const float* __restrict__ b1,
    __hip_bfloat16* __restrict__ h1s)
{
    __shared__ short sxb[128*130];
    __shared__ float sp1[256], sp2[256];
    const int t = threadIdx.x;
    const int lane = t & 63, w = t >> 6;
    const int l15 = lane & 15, q4 = (lane >> 4)*4, ko = (lane >> 4)*8;
    const int mhalf = w & 1, phalf = w >> 1;
    const int pbase = blockIdx.x * 128;
    const int b = pbase >> 16;            // 0/1 within pair
    const int hw0 = pbase & 65535;
    const int pxs = t & 127, chalf = t >> 7;
    const float* xb = outb2 + (size_t)b*CHW + (size_t)chalf*64*HW + hw0 + pxs;
    unsigned* srow = (unsigned*)sxb + pxs*65 + chalf*32;
    float s1 = 0.f, s2 = 0.f;
    #pragma unroll 8
    for (int j = 0; j < 32; ++j) {
        float v0 = xb[(size_t)(2*j)*HW];
        float v1 = xb[(size_t)(2*j+1)*HW];
        s1 += v0 + v1; s2 += v0*v0 + v1*v1;
        __hip_bfloat162 pk = __float22bfloat162_rn(make_float2(v0, v1));
        srow[j] = *(unsigned*)&pk;
    }
    sp1[chalf*128 + pxs] = s1;
    sp2[chalf*128 + pxs] = s2;
    __syncthreads();
    const float s1t = sp1[pxs] + sp1[128 + pxs];
    const float s2t = sp2[pxs] + sp2[128 + pxs];
    const float mean = s1t * 0.0078125f;
    const float rstd = rsqrtf(s2t*0.0078125f - mean*mean + 1e-6f);
    #pragma unroll 8
    for (int j = 0; j < 32; ++j) {
        unsigned u = srow[j];
        float v0 = __uint_as_float(u << 16);
        float v1 = __uint_as_float(u & 0xffff0000u);
        const int c = chalf*64 + 2*j;
        v0 = (v0 - mean)*rstd*n2w[c]   + n2b[c];
        v1 = (v1 - mean)*rstd*n2w[c+1] + n2b[c+1];
        __hip_bfloat162 pk = __float22bfloat162_rn(make_float2(v0, v1));
        srow[j] = *(unsigned*)&pk;
    }
    __syncthreads();
    const short* w1s = (const short*)w1;
    __hip_bfloat16* hb = h1s + (size_t)b*512*HW + hw0;
    for (int mc = 0; mc < 4; ++mc) {
        f32x4 acc[4][4];
        #pragma unroll
        for (int mt = 0; mt < 4; ++mt)
            #pragma unroll
            for (int nt = 0; nt < 4; ++nt)
                acc[mt][nt] = (f32x4){0.f,0.f,0.f,0.f};
        #pragma unroll
        for (int kc = 0; kc < 4; ++kc) {
            bf16x8 bfrag[4];
            #pragma unroll
            for (int nt = 0; nt < 4; ++nt) {
                const int px = phalf*64 + nt*16 + l15;
                bfrag[nt] = *(const bf16x8*)(sxb + px*130 + kc*32 + ko);
            }
            #pragma unroll
            for (int mt = 0; mt < 4; ++mt) {
                const int m = mc*128 + mhalf*64 + mt*16 + l15;
                bf16x8 af = *(const bf16x8*)(w1s + m*128 + kc*32 + ko);
                #pragma unroll
                for (int nt = 0; nt < 4; ++nt)
                    acc[mt][nt] = __builtin_amdgcn_mfma_f32_16x16x32_bf16(af, bfrag[nt], acc[mt][nt], 0, 0, 0);
            }
        }
        #pragma unroll
        for (int mt = 0; mt < 4; ++mt)
            #pragma unroll
            for (int nt = 0; nt < 4; ++nt) {
                const int px = phalf*64 + nt*16 + l15;
                #pragma unroll
                for (int r = 0; r < 4; ++r) {
                    const int o = mc*128 + mhalf*64 + mt*16 + q4 + r;
                    const float v = geluf(acc[mt][nt][r] + b1[o]);
                    hb[(size_t)o*HW + px] = __float2bfloat16(v);
                }
            }
    }
}

// ---------------- K5a: depthwise 3x3 + GELU -> h2 pair-packed (2-batch grid 8192) ----
__global__ __launch_bounds__(256) void k_dwconv(
    const __hip_bfloat16* __restrict__ h1s,   // 2 slabs of [512][HW] bf16
    unsigned* __restrict__ h2u,               // 2 slabs of [256][HW] pair-packed
    const float* __restrict__ dwf, const float* __restrict__ dwb)
{
    __shared__ short sh[2*18*260];            // 2 ch x 18 rows x (2 + 256 + 1 + pad) cols
    const int t = threadIdx.x;
    const int blk = blockIdx.x;
    const int b   = blk >> 12;                // 0/1 within pair
    const int rem = blk & 4095;
    const int rb = rem & 15;
    const int cp = rem >> 4;                  // channel pair 0..255
    const int row0 = rb * 16;
    const __hip_bfloat16* h1b = h1s + (size_t)b*512*HW;
    #pragma unroll
    for (int ch = 0; ch < 2; ++ch) {
        const __hip_bfloat16* src = h1b + (size_t)(cp*2 + ch)*HW;
        #pragma unroll
        for (int i = 0; i < 9; ++i) {
            const int idx = t + i*256;
            const int r = idx >> 7;           // 0..17
            const int u = idx & 127;          // uint col (2 pixels)
            const int y = row0 - 1 + r;
            unsigned v = 0u;
            if ((unsigned)y < 256u) v = *(const unsigned*)(src + (size_t)y*256 + u*2);
            *(unsigned*)(&sh[ch*4680 + r*260 + 2 + u*2]) = v;
        }
    }
    if (t < 72) {
        const int ch = t / 36, q = t - ch*36;
        const int r = q >> 1;
        sh[ch*4680 + r*260 + ((q & 1) ? 258 : 1)] = 0;
    }
    __syncthreads();
    float wt[2][9], bs[2];
    #pragma unroll
    for (int ch = 0; ch < 2; ++ch) {
        const float* dwc = dwf + (size_t)(cp*2 + ch)*9;
        #pragma unroll
        for (int k = 0; k < 9; ++k) wt[ch][k] = dwc[k];
        bs[ch] = dwb[cp*2 + ch];
    }
    const int xp = (t & 127) * 2;   // this thread's output column pair
    const int rh = t >> 7;          // row half (8 rows each)
    unsigned* h2b = h2u + (size_t)b*256*HW;
    #pragma unroll
    for (int r = 0; r < 8; ++r) {
        const int orow = rh*8 + r;            // 0..15 within block
        const int y = row0 + orow;
        float res[2][2];
        #pragma unroll
        for (int ch = 0; ch < 2; ++ch) {
            const short* base = sh + ch*4680 + orow*260 + xp + 1;
            float a[3][4];
            #pragma unroll
            for (int dy = 0; dy < 3; ++dy)
                #pragma unroll
                for (int k = 0; k < 4; ++k)
                    a[dy][k] = __uint_as_float((unsigned)(unsigned short)base[dy*260 + k] << 16);
            #pragma unroll
            for (int xj = 0; xj < 2; ++xj) {
                float s = bs[ch];
                #pragma unroll
                for (int dy = 0; dy < 3; ++dy)
                    #pragma unroll
                    for (int dx = 0; dx < 3; ++dx)
                        s = fmaf(a[dy][xj+dx], wt[ch][dy*3+dx], s);
                res[ch][xj] = geluf(s);
            }
        }
        __hip_bfloat162 pk0 = __float22bfloat162_rn(make_float2(res[0][0], res[1][0]));
        __hip_bfloat162 pk1 = __float22bfloat162_rn(make_float2(res[0][1], res[1][1]));
        uint2 st;
        st.x = *(unsigned*)&pk0;
        st.y = *(unsigned*)&pk1;
        *(uint2*)(h2b + (size_t)cp*HW + (size_t)y*256 + xp) = st;
    }
}

// ---------------- K5b: FFN2 GEMM (128 out x 512 in) + bias + residual (2-batch grid 1024) ----
__global__ __launch_bounds__(256,3) void k_ffn2g(
    const unsigned* __restrict__ h2u, const __hip_bfloat16* __restrict__ w2b,
    const float* __restrict__ b2, float* __restrict__ outb2)
{
    __shared__ short sxb[128*130];            // [px][128 ch + 2 pad]
    const int t = threadIdx.x;
    const int lane = t & 63, w = t >> 6;
    const int l15 = lane & 15, q4 = (lane >> 4)*4, ko = (lane >> 4)*8;
    const int mhalf = w & 1, phalf = w >> 1;
    const int pbase = blockIdx.x * 128;
    const int b = pbase >> 16;                // 0/1 within pair
    const int hw0 = pbase & 65535;
    const int pxs = t & 127;                  // staging: this thread's pixel row
    const int chalf = t >> 7;                 // staging: channel-pair half
    const unsigned* h2b = h2u + (size_t)b*256*HW;
    f32x4 acc[4][4];
    #pragma unroll
    for (int mt = 0; mt < 4; ++mt)
        #pragma unroll
        for (int nt = 0; nt < 4; ++nt)
            acc[mt][nt] = (f32x4){0.f,0.f,0.f,0.f};
    const short* w2s = (const short*)w2b;
    for (int k4 = 0; k4 < 4; ++k4) {
        if (k4) __syncthreads();
        const unsigned* hsrc = h2b + (size_t)(k4*64 + chalf*32)*HW + hw0 + pxs;
        unsigned* sdst = (unsigned*)sxb + pxs*65 + chalf*32;
        #pragma unroll
        for (int c = 0; c < 32; ++c)
            sdst[c] = hsrc[(size_t)c*HW];
        __syncthreads();
        #pragma unroll
        for (int kc = 0; kc < 4; ++kc) {
            bf16x8 bfrag[4];
            #pragma unroll
            for (int nt = 0; nt < 4; ++nt) {
                const int px = phalf*64 + nt*16 + l15;
                bfrag[nt] = *(const bf16x8*)(sxb + px*130 + kc*32 + ko);
            }
            #pragma unroll
            for (int mt = 0; mt < 4; ++mt) {
                const int m = mhalf*64 + mt*16 + l15;
                bf16x8 af = *(const bf16x8*)(w2s + (size_t)m*512 + k4*128 + kc*32 + ko);
                #pragma unroll
                for (int nt = 0; nt < 4; ++nt)
                    acc[mt][nt] = __builtin_amdgcn_mfma_f32_16x16x32_bf16(af, bfrag[nt], acc[mt][nt], 0, 0, 0);
            }
        }
    }
    float* ob = outb2 + (size_t)b*CHW;
    #pragma unroll
    for (int mt = 0; mt < 4; ++mt)
        #pragma unroll
        for (int nt = 0; nt < 4; ++nt) {
            const int px = hw0 + phalf*64 + nt*16 + l15;
            #pragma unroll
            for (int r = 0; r < 4; ++r) {
                const int o = mhalf*64 + mt*16 + q4 + r;
                ob[(size_t)o*HW + px] = acc[mt][nt][r] + b2[o] + ob[(size_t)o*HW + px];
            }
        }
}

extern "C" void kernel_launch(void* const* d_in, const int* in_sizes, int n_in,
                              void* d_out, int out_size, void* d_ws, size_t ws_size,
                              hipStream_t stream) {
    const float* x      = (const float*)d_in[0];
    const float* l0     = (const float*)d_in[1];
    const float* n1w    = (const float*)d_in[2];
    const float* n1b    = (const float*)d_in[3];
    const float* n2w    = (const float*)d_in[4];
    const float* n2b    = (const float*)d_in[5];
    const float* qkv_w  = (const float*)d_in[6];
    const float* gate_w = (const float*)d_in[7];
    const float* gate_b = (const float*)d_in[8];
    const float* proj_w = (const float*)d_in[9];
    const float* proj_b = (const float*)d_in[10];
    const float* ffn_w1 = (const float*)d_in[11];
    const float* ffn_b1 = (const float*)d_in[12];
    const float* ffn_dw = (const float*)d_in[13];
    const float* ffn_dwb= (const float*)d_in[14];
    const float* ffn_w2 = (const float*)d_in[15];
    const float* ffn_b2 = (const float*)d_in[16];

    float* out = (float*)d_out;
    // ws layout (max byte touched = 268,828,672 — identical to the proven footprint):
    //   phase 1 (qkv/attn/proj): qkv [0,192 MiB); apack bf16 attn-out [192,256 MiB)
    //   phase 2 (ffn, per 2-batch pair): h1 2 slabs [0,128 MiB); h2 2 slabs [128,256 MiB)
    //   weights [256 MiB,+384 KiB)
    __hip_bfloat16* qkvb = (__hip_bfloat16*)d_ws;
    unsigned* apack      = (unsigned*)((char*)d_ws + 201326592);         // 192 MiB
    __hip_bfloat16* h1s  = (__hip_bfloat16*)d_ws;                        // 0 MiB (2 slabs)
    unsigned* h2u        = (unsigned*)((char*)d_ws + 134217728);         // 128 MiB (2 slabs)
    char* wbase = (char*)d_ws + 268435456;
    __hip_bfloat16* qkvw_b = (__hip_bfloat16*)(wbase);
    __hip_bfloat16* projw_b= (__hip_bfloat16*)(wbase + 98304);
    __hip_bfloat16* w1b    = (__hip_bfloat16*)(wbase + 131072);
    __hip_bfloat16* w2b    = (__hip_bfloat16*)(wbase + 262144);

    k_cvt<<<dim3(192), dim3(256), 0, stream>>>(qkv_w, qkvw_b, 49152);
    k_cvt<<<dim3(64),  dim3(256), 0, stream>>>(proj_w, projw_b, 16384);
    k_cvt<<<dim3(256), dim3(256), 0, stream>>>(ffn_w1, w1b, 65536);
    k_cvt<<<dim3(256), dim3(256), 0, stream>>>(ffn_w2, w2b, 65536);

    k_ln_qkv_mfma<<<dim3(2048), dim3(512), 0, stream>>>(x, l0, n1w, n1b, qkvw_b, gate_w, gate_b, qkvb);
    k_attn       <<<dim3(8192), dim3(256), 0, stream>>>(qkvb, apack);
    k_proj_mfma  <<<dim3(2048), dim3(256), 0, stream>>>(x, apack, projw_b, proj_b, out);
    for (int b2 = 0; b2 < 2; ++b2) {
        float* outp = out + (size_t)b2*2*CHW;
        k_ffn1_mfma<<<dim3(1024), dim3(256), 0, stream>>>(outp, n2w, n2b, w1b, ffn_b1, h1s);
        k_dwconv   <<<dim3(8192), dim3(256), 0, stream>>>(h1s, h2u, ffn_dw, ffn_dwb);
        k_ffn2g    <<<dim3(1024), dim3(256), 0, stream>>>(h2u, w2b, ffn_b2, outp);
    }
}